// Round 4
// baseline (636.940 us; speedup 1.0000x reference)
//
#include <hip/hip_runtime.h>
#include <hip/hip_bf16.h>

#define NNODES 100000
#define NEDGES 1000000
#define HID 128
#define OUTF 16
#define NB 16       // dst-range buckets for CSR build
#define BCAP 81920  // per-bucket stage capacity (expected ~62500)
#define KB 64       // blocks per bucket in fill2
#define BZT 1024    // bucketize block size
#define AGG_BN 128  // nodes per agg block (per slice)

typedef __attribute__((ext_vector_type(8))) short short8;
typedef __attribute__((ext_vector_type(4))) float floatx4;
typedef unsigned int uint32;
typedef unsigned long long ull;
typedef unsigned short ushort16;

__device__ __forceinline__ float blo(uint32 u) { return __uint_as_float(u << 16); }
__device__ __forceinline__ float bhi(uint32 u) { return __uint_as_float(u & 0xffff0000u); }
__device__ __forceinline__ ushort16 f2b(float f) {
    __hip_bfloat16 h = __float2bfloat16(f);
    return *reinterpret_cast<ushort16*>(&h);
}
__device__ __forceinline__ uint32 pack2(float a, float b) {
    return (uint32)f2b(a) | ((uint32)f2b(b) << 16);
}

// ---------------- CSR build ----------------
// Pass A: histogram (atomic returns per-node rank) + LDS-reordered bucket compaction.
// Staged word: lo32 = src, hi32 = dst | (rank<<17).

__global__ __launch_bounds__(BZT) void bucketize(const int* __restrict__ src,
                                                 const int* __restrict__ dst,
                                                 int* __restrict__ counts,
                                                 int* __restrict__ bcursor,
                                                 ull* __restrict__ stage, int E) {
    __shared__ int cnt[NB], lbase[NB], gbase[NB];
    __shared__ int2 buf[BZT];
    __shared__ unsigned char bb[BZT];
    int t = threadIdx.x;
    int e0 = blockIdx.x * BZT;
    int e = e0 + t;
    if (t < NB) cnt[t] = 0;
    __syncthreads();
    int s = 0; unsigned y = 0; int b = 0, r = 0;
    bool valid = e < E;
    if (valid) {
        s = src[e];
        int d = dst[e];
        int rk = atomicAdd(&counts[d], 1);        // per-node rank (also the histogram)
        y = (unsigned)d | ((unsigned)rk << 17);
        b = (int)((unsigned)d * NB / NNODES);
        r = atomicAdd(&cnt[b], 1);
    }
    __syncthreads();
    if (t == 0) {
        int run = 0;
        for (int i = 0; i < NB; i++) { lbase[i] = run; run += cnt[i]; }
    }
    __syncthreads();
    if (valid) {
        int p = lbase[b] + r;
        buf[p] = make_int2(s, (int)y);
        bb[p] = (unsigned char)b;
    }
    if (t < NB) gbase[t] = atomicAdd(&bcursor[t], cnt[t]);
    __syncthreads();
    int nvalid = min(BZT, E - e0);
    if (t < nvalid) {
        int b2 = bb[t];
        int2 sd = buf[t];
        int pos = gbase[b2] + (t - lbase[b2]);
        if (pos < BCAP) {
            ull val = (ull)(unsigned)sd.x | ((ull)(unsigned)sd.y << 32);
            __builtin_nontemporal_store(val, &stage[(size_t)b2 * BCAP + pos]);
        }
    }
}

// Pass B: atomic-free scatter within one bucket's csr window; buckets pinned to XCDs.
__global__ __launch_bounds__(256) void fill2(const ull* __restrict__ stage,
                                             const int* __restrict__ bcursor,
                                             const int* __restrict__ offs,
                                             int* __restrict__ csr) {
    int blk = blockIdx.x;
    int b = (blk & 7) + 8 * ((blk >> 3) & 1);  // home XCD = b%8
    int slot = blk >> 4;
    int cntb = min(bcursor[b], BCAP);
    int per = (cntb + KB - 1) / KB;
    int s0 = slot * per;
    int s1 = min(s0 + per, cntb);
    const ull* st = stage + (size_t)b * BCAP;
    for (int i = s0 + threadIdx.x; i < s1; i += 256) {
        ull v = __builtin_nontemporal_load(&st[i]);
        int s = (int)(v & 0xffffffffu);
        unsigned y = (unsigned)(v >> 32);
        int d = (int)(y & 0x1ffffu);
        int r = (int)(y >> 17);
        csr[offs[d] + r] = s;
    }
}

__global__ void scan1(const int* __restrict__ counts, int* __restrict__ offs,
                      int* __restrict__ bsum, int N) {
    __shared__ int tmp[256];
    int t = threadIdx.x;
    int i = blockIdx.x * 256 + t;
    int v = (i < N) ? counts[i] : 0;
    tmp[t] = v;
    __syncthreads();
    for (int d = 1; d < 256; d <<= 1) {
        int add = (t >= d) ? tmp[t - d] : 0;
        __syncthreads();
        tmp[t] += add;
        __syncthreads();
    }
    if (i < N) offs[i] = tmp[t] - v;
    if (t == 255) bsum[blockIdx.x] = tmp[255];
}

__global__ void scan2(int* __restrict__ bsum, int nb) {
    __shared__ int tmp[512];
    int t = threadIdx.x;
    int v = (t < nb) ? bsum[t] : 0;
    tmp[t] = v;
    __syncthreads();
    for (int d = 1; d < 512; d <<= 1) {
        int add = (t >= d) ? tmp[t - d] : 0;
        __syncthreads();
        tmp[t] += add;
        __syncthreads();
    }
    if (t < nb) bsum[t] = tmp[t] - v;
}

__global__ void scan3(int* __restrict__ offs, const int* __restrict__ bsum,
                      const int* __restrict__ counts, float* __restrict__ inv,
                      int N, int E) {
    int i = blockIdx.x * 256 + threadIdx.x;
    if (i < N) {
        offs[i] += bsum[blockIdx.x];
        inv[i] = 1.0f / (float)(counts[i] + 1);
    }
    if (i == 0) offs[N] = E;
}

// ---------------- weight pack: W[128x128] fp32 -> MFMA B-fragment order bf16 ----------------

__global__ void pack_w(const float* __restrict__ W, ushort16* __restrict__ Wp) {
    int b = blockIdx.x;      // 0..31 = nt*4 + ks
    int lane = threadIdx.x;  // 64
    int nt = b >> 2, ks = b & 3;
    int n = nt * 16 + (lane & 15);
    int kbase = ks * 32 + ((lane >> 4) << 3);
    ushort16 tmp[8];
#pragma unroll
    for (int i = 0; i < 8; i++) tmp[i] = f2b(W[(size_t)(kbase + i) * HID + n]);
    *(uint4*)&Wp[((size_t)b * 64 + lane) * 8] = *(uint4*)tmp;
}

// ---------------- MFMA GEMM: Z(sliced [8][N][16] bf16) = A @ W ----------------
// A: AF32 ? dense fp32 [N][128] : sliced bf16 [8][N][16]

template <int AF32>
__global__ __launch_bounds__(256) void gemm_mfma(const void* __restrict__ Av,
                                                 const ushort16* __restrict__ Wp,
                                                 ushort16* __restrict__ Z, int M) {
    __shared__ __align__(16) ushort16 Wl[32 * 64 * 8];  // 32 KB
    int t = threadIdx.x;
    const uint4* wp4 = (const uint4*)Wp;
    uint4* wl4 = (uint4*)Wl;
#pragma unroll
    for (int p = 0; p < 8; p++) wl4[t + p * 256] = wp4[t + p * 256];
    __syncthreads();

    int wv = t >> 6, lane = t & 63;
    int row = blockIdx.x * 64 + wv * 16 + (lane & 15);
    int rowc = min(row, M - 1);
    int kb = (lane >> 4) << 3;  // 0,8,16,24

    short8 a[4];
    if (AF32) {
        const float* A = (const float*)Av;
#pragma unroll
        for (int ks = 0; ks < 4; ks++) {
            const float* p = A + (size_t)rowc * HID + ks * 32 + kb;
            floatx4 lo = *(const floatx4*)p;
            floatx4 hi = *(const floatx4*)(p + 4);
            union { short8 s; ushort16 u[8]; } cv;
            cv.u[0] = f2b(lo.x); cv.u[1] = f2b(lo.y); cv.u[2] = f2b(lo.z); cv.u[3] = f2b(lo.w);
            cv.u[4] = f2b(hi.x); cv.u[5] = f2b(hi.y); cv.u[6] = f2b(hi.z); cv.u[7] = f2b(hi.w);
            a[ks] = cv.s;
        }
    } else {
        const ushort16* A = (const ushort16*)Av;
        int sl = kb >> 4, soff = kb & 8;
#pragma unroll
        for (int ks = 0; ks < 4; ks++) {
            int slice = ks * 2 + sl;
            a[ks] = *(const short8*)(A + ((size_t)slice * NNODES + rowc) * 16 + soff);
        }
    }

    floatx4 acc[8];
#pragma unroll
    for (int nt = 0; nt < 8; nt++) acc[nt] = (floatx4){0.f, 0.f, 0.f, 0.f};

#pragma unroll
    for (int nt = 0; nt < 8; nt++) {
#pragma unroll
        for (int ks = 0; ks < 4; ks++) {
            short8 b = *(const short8*)&Wl[(size_t)(((nt << 2) | ks) * 64 + lane) * 8];
            acc[nt] = __builtin_amdgcn_mfma_f32_16x16x32_bf16(a[ks], b, acc[nt], 0, 0, 0);
        }
    }

    int orow = blockIdx.x * 64 + wv * 16 + ((lane >> 4) << 2);
    int col = lane & 15;
#pragma unroll
    for (int i = 0; i < 4; i++) {
        int r = orow + i;
        if (r < M) {
#pragma unroll
            for (int nt = 0; nt < 8; nt++)
                Z[((size_t)nt * NNODES + r) * 16 + col] = f2b(acc[nt][i]);
        }
    }
}

// ---------------- sliced aggregate: slice = blockIdx%8 (pinned to its XCD's L2) ----------------
// Z,H sliced [8][N][8] uint32 (16 bf16). 8 lanes per node; 32 nodes per 256-thr block pass.

__global__ __launch_bounds__(256) void agg_sliced(const uint32* __restrict__ Z,
                                                  const int* __restrict__ offs,
                                                  const int* __restrict__ csr,
                                                  const float* __restrict__ inv,
                                                  const float* __restrict__ bias,
                                                  uint32* __restrict__ H, int N) {
    int s = blockIdx.x & 7;
    int chunk = blockIdx.x >> 3;
    int t = threadIdx.x;
    int grp = t >> 3;            // 0..31
    int l4 = t & 7;              // feature-pair index
    int lanebase = t & 56;       // group base within wave
    const uint32* Zs = Z + (size_t)s * NNODES * 8;
    uint32* Hs = H + (size_t)s * NNODES * 8;
    const float2* bs = (const float2*)(bias + s * 16);
    float2 bb = bs[l4];
#pragma unroll
    for (int it = 0; it < AGG_BN / 32; ++it) {
        int v = chunk * AGG_BN + it * 32 + grp;
        bool act = v < N;
        float ax = 0.f, ay = 0.f, iv = 0.f;
        int beg = 0, cnt = 0;
        if (act) {
            uint32 sv = Zs[(size_t)v * 8 + l4];
            ax = blo(sv); ay = bhi(sv);
            beg = offs[v];
            cnt = offs[v + 1] - beg;
            iv = inv[v];
        }
        for (int j = 0; j < cnt; j += 8) {
            int m = min(cnt - j, 8);
            int idxr = 0;
            if (l4 < m) idxr = __builtin_nontemporal_load(&csr[beg + j + l4]);
#pragma unroll
            for (int q = 0; q < 8; q++) {
                if (q < m) {
                    int u = __shfl(idxr, lanebase + q, 64);
                    uint32 g = Zs[(size_t)u * 8 + l4];
                    ax += blo(g); ay += bhi(g);
                }
            }
        }
        if (act) {
            float rx = fmaxf(ax * iv + bb.x, 0.f);
            float ry = fmaxf(ay * iv + bb.y, 0.f);
            __builtin_nontemporal_store(pack2(rx, ry), &Hs[(size_t)v * 8 + l4]);
        }
    }
}

// ---------------- layer 5: Z16[N][16] bf16 = H(sliced) @ W5 ----------------

__global__ __launch_bounds__(256) void gemm16(const uint32* __restrict__ A,  // sliced [8][N][8]
                                              const float* __restrict__ W5,
                                              uint32* __restrict__ Z16, int M) {
    __shared__ float Ws[HID * OUTF];  // 8 KB
    int t = threadIdx.x;
    for (int i = t; i < HID * OUTF; i += 256) Ws[i] = W5[i];
    __syncthreads();
    int gid = blockIdx.x * 256 + t;
    int r = gid >> 3, cp = gid & 7;
    if (r >= M) return;
    float a0 = 0.f, a1 = 0.f;
#pragma unroll
    for (int s8 = 0; s8 < 8; s8++) {
        const uint32* ar = A + ((size_t)s8 * NNODES + r) * 8;
#pragma unroll
        for (int k = 0; k < 8; k++) {
            uint32 u = ar[k];
            float f0 = blo(u), f1 = bhi(u);
            a0 += f0 * Ws[(s8 * 16 + 2 * k) * OUTF + 2 * cp] +
                  f1 * Ws[(s8 * 16 + 2 * k + 1) * OUTF + 2 * cp];
            a1 += f0 * Ws[(s8 * 16 + 2 * k) * OUTF + 2 * cp + 1] +
                  f1 * Ws[(s8 * 16 + 2 * k + 1) * OUTF + 2 * cp + 1];
        }
    }
    Z16[(size_t)r * 8 + cp] = pack2(a0, a1);
}

// ---------------- layer 5 aggregate + bias + log_softmax (8 lanes/node) ----------------

__global__ __launch_bounds__(256) void agg16_lsm(const uint32* __restrict__ Z16,
                                                 const int* __restrict__ offs,
                                                 const int* __restrict__ csr,
                                                 const float* __restrict__ inv,
                                                 const float* __restrict__ b5,
                                                 float* __restrict__ out, int N) {
    int gid = blockIdx.x * 256 + threadIdx.x;
    int v = gid >> 3, l = gid & 7;
    if (v >= N) return;
    int lanebase = threadIdx.x & 56;
    uint32 sv = Z16[(size_t)v * 8 + l];
    float ax = blo(sv), ay = bhi(sv);
    int beg = offs[v], cnt = offs[v + 1] - beg;
    for (int j = 0; j < cnt; j += 8) {
        int m = min(cnt - j, 8);
        int idxr = 0;
        if (l < m) idxr = __builtin_nontemporal_load(&csr[beg + j + l]);
#pragma unroll
        for (int q = 0; q < 8; q++) {
            if (q < m) {
                int u = __shfl(idxr, lanebase + q, 64);
                uint32 g = Z16[(size_t)u * 8 + l];
                ax += blo(g); ay += bhi(g);
            }
        }
    }
    float iv = inv[v];
    float2 bb = *(const float2*)(b5 + 2 * l);
    float vx = ax * iv + bb.x, vy = ay * iv + bb.y;
    float mm = fmaxf(vx, vy);
#pragma unroll
    for (int d = 1; d < 8; d <<= 1) mm = fmaxf(mm, __shfl_xor(mm, d, 8));
    float ex = expf(vx - mm), ey = expf(vy - mm);
    float ss = ex + ey;
#pragma unroll
    for (int d = 1; d < 8; d <<= 1) ss += __shfl_xor(ss, d, 8);
    float ls = logf(ss);
    *(float2*)&out[(size_t)v * OUTF + 2 * l] = make_float2(vx - mm - ls, vy - mm - ls);
}

// ---------------- launch ----------------

extern "C" void kernel_launch(void* const* d_in, const int* in_sizes, int n_in,
                              void* d_out, int out_size, void* d_ws, size_t ws_size,
                              hipStream_t stream) {
    const float* x   = (const float*)d_in[0];
    const int*   src = (const int*)d_in[1];
    const int*   dst = (const int*)d_in[2];
    const float* W1 = (const float*)d_in[3];
    const float* b1 = (const float*)d_in[4];
    const float* W2 = (const float*)d_in[5];
    const float* b2 = (const float*)d_in[6];
    const float* W3 = (const float*)d_in[7];
    const float* b3 = (const float*)d_in[8];
    const float* W4 = (const float*)d_in[9];
    const float* b4 = (const float*)d_in[10];
    const float* W5 = (const float*)d_in[11];
    const float* b5 = (const float*)d_in[12];

    char* ws = (char*)d_ws;
    size_t off = 0;
    auto alloc = [&](size_t bytes) {
        void* p = ws + off;
        off = (off + bytes + 255) & ~(size_t)255;
        return p;
    };
    ushort16* zb   = (ushort16*)alloc((size_t)NNODES * HID * 2);
    ushort16* hb   = (ushort16*)alloc((size_t)NNODES * HID * 2);
    uint32*   z16b = (uint32*)alloc((size_t)NNODES * OUTF * 2);
    int*      counts = (int*)alloc((size_t)NNODES * 4);
    int*      offs   = (int*)alloc((size_t)(NNODES + 1) * 4);
    int*      bsum   = (int*)alloc(512 * 4);
    int*      csr    = (int*)alloc((size_t)NEDGES * 4);
    float*    invd   = (float*)alloc((size_t)NNODES * 4);
    ull*      stage  = (ull*)alloc((size_t)NB * BCAP * 8);
    int*      bcursor = (int*)alloc(NB * 4);
    ushort16* Wp1 = (ushort16*)alloc((size_t)HID * HID * 2);
    ushort16* Wp2 = (ushort16*)alloc((size_t)HID * HID * 2);
    ushort16* Wp3 = (ushort16*)alloc((size_t)HID * HID * 2);
    ushort16* Wp4 = (ushort16*)alloc((size_t)HID * HID * 2);
    (void)ws_size; (void)in_sizes; (void)n_in; (void)out_size;

    const int N = NNODES, E = NEDGES;
    int nb = (N + 255) / 256;

    // CSR build
    hipMemsetAsync(counts, 0, (size_t)N * 4, stream);
    hipMemsetAsync(bcursor, 0, NB * 4, stream);
    bucketize<<<(E + BZT - 1) / BZT, BZT, 0, stream>>>(src, dst, counts, bcursor, stage, E);
    scan1<<<nb, 256, 0, stream>>>(counts, offs, bsum, N);
    scan2<<<1, 512, 0, stream>>>(bsum, nb);
    scan3<<<nb, 256, 0, stream>>>(offs, bsum, counts, invd, N, E);
    fill2<<<NB * KB, 256, 0, stream>>>(stage, bcursor, offs, csr);

    // pack weights
    pack_w<<<32, 64, 0, stream>>>(W1, Wp1);
    pack_w<<<32, 64, 0, stream>>>(W2, Wp2);
    pack_w<<<32, 64, 0, stream>>>(W3, Wp3);
    pack_w<<<32, 64, 0, stream>>>(W4, Wp4);

    int gemmGrid = (N + 63) / 64;
    int aggGrid  = 8 * ((N + AGG_BN - 1) / AGG_BN);

    gemm_mfma<1><<<gemmGrid, 256, 0, stream>>>((const void*)x, Wp1, zb, N);
    agg_sliced<<<aggGrid, 256, 0, stream>>>((const uint32*)zb, offs, csr, invd, b1, (uint32*)hb, N);

    gemm_mfma<0><<<gemmGrid, 256, 0, stream>>>((const void*)hb, Wp2, zb, N);
    agg_sliced<<<aggGrid, 256, 0, stream>>>((const uint32*)zb, offs, csr, invd, b2, (uint32*)hb, N);

    gemm_mfma<0><<<gemmGrid, 256, 0, stream>>>((const void*)hb, Wp3, zb, N);
    agg_sliced<<<aggGrid, 256, 0, stream>>>((const uint32*)zb, offs, csr, invd, b3, (uint32*)hb, N);

    gemm_mfma<0><<<gemmGrid, 256, 0, stream>>>((const void*)hb, Wp4, zb, N);
    agg_sliced<<<aggGrid, 256, 0, stream>>>((const uint32*)zb, offs, csr, invd, b4, (uint32*)hb, N);

    gemm16<<<(N * 8 + 255) / 256, 256, 0, stream>>>((const uint32*)hb, W5, z16b, N);
    agg16_lsm<<<(N * 8 + 255) / 256, 256, 0, stream>>>(z16b, offs, csr, invd, b5,
                                                       (float*)d_out, N);
}

// Round 5
// 505.855 us; speedup vs baseline: 1.2591x; 1.2591x over previous
//
#include <hip/hip_runtime.h>
#include <hip/hip_bf16.h>

#define NNODES 100000
#define NEDGES 1000000
#define HID 128
#define OUTF 16
#define NB 16       // dst-range buckets for CSR build
#define BCAP 81920  // per-bucket stage capacity (expected ~62500)
#define KB 64       // blocks per bucket in fill2
#define BZT 1024    // bucketize block size
#define AGG_BN 128  // nodes per agg block (per slice)

typedef __attribute__((ext_vector_type(8))) short short8;
typedef __attribute__((ext_vector_type(4))) float floatx4;
typedef unsigned int uint32;
typedef unsigned long long ull;
typedef unsigned short ushort16;

__device__ __forceinline__ float blo(uint32 u) { return __uint_as_float(u << 16); }
__device__ __forceinline__ float bhi(uint32 u) { return __uint_as_float(u & 0xffff0000u); }
__device__ __forceinline__ ushort16 f2b(float f) {
    __hip_bfloat16 h = __float2bfloat16(f);
    return *reinterpret_cast<ushort16*>(&h);
}
__device__ __forceinline__ uint32 pack2(float a, float b) {
    return (uint32)f2b(a) | ((uint32)f2b(b) << 16);
}

// ---------------- CSR build ----------------
// Pass A: histogram (atomic returns per-node rank) + LDS-reordered bucket compaction.
// Staged word: lo32 = src, hi32 = dst | (rank<<17).

__global__ __launch_bounds__(BZT) void bucketize(const int* __restrict__ src,
                                                 const int* __restrict__ dst,
                                                 int* __restrict__ counts,
                                                 int* __restrict__ bcursor,
                                                 ull* __restrict__ stage, int E) {
    __shared__ int cnt[NB], lbase[NB], gbase[NB];
    __shared__ int2 buf[BZT];
    __shared__ unsigned char bb[BZT];
    int t = threadIdx.x;
    int e0 = blockIdx.x * BZT;
    int e = e0 + t;
    if (t < NB) cnt[t] = 0;
    __syncthreads();
    int s = 0; unsigned y = 0; int b = 0, r = 0;
    bool valid = e < E;
    if (valid) {
        s = src[e];
        int d = dst[e];
        int rk = atomicAdd(&counts[d], 1);        // per-node rank (also the histogram)
        y = (unsigned)d | ((unsigned)rk << 17);
        b = (int)((unsigned)d * NB / NNODES);
        r = atomicAdd(&cnt[b], 1);
    }
    __syncthreads();
    if (t == 0) {
        int run = 0;
        for (int i = 0; i < NB; i++) { lbase[i] = run; run += cnt[i]; }
    }
    __syncthreads();
    if (valid) {
        int p = lbase[b] + r;
        buf[p] = make_int2(s, (int)y);
        bb[p] = (unsigned char)b;
    }
    if (t < NB) gbase[t] = atomicAdd(&bcursor[t], cnt[t]);
    __syncthreads();
    int nvalid = min(BZT, E - e0);
    if (t < nvalid) {
        int b2 = bb[t];
        int2 sd = buf[t];
        int pos = gbase[b2] + (t - lbase[b2]);
        if (pos < BCAP) {
            ull val = (ull)(unsigned)sd.x | ((ull)(unsigned)sd.y << 32);
            __builtin_nontemporal_store(val, &stage[(size_t)b2 * BCAP + pos]);
        }
    }
}

// Pass B: atomic-free scatter within one bucket's csr window; buckets pinned to XCDs.
__global__ __launch_bounds__(256) void fill2(const ull* __restrict__ stage,
                                             const int* __restrict__ bcursor,
                                             const int* __restrict__ offs,
                                             int* __restrict__ csr) {
    int blk = blockIdx.x;
    int b = (blk & 7) + 8 * ((blk >> 3) & 1);  // home XCD = b%8
    int slot = blk >> 4;
    int cntb = min(bcursor[b], BCAP);
    int per = (cntb + KB - 1) / KB;
    int s0 = slot * per;
    int s1 = min(s0 + per, cntb);
    const ull* st = stage + (size_t)b * BCAP;
    for (int i = s0 + threadIdx.x; i < s1; i += 256) {
        ull v = __builtin_nontemporal_load(&st[i]);
        int s = (int)(v & 0xffffffffu);
        unsigned y = (unsigned)(v >> 32);
        int d = (int)(y & 0x1ffffu);
        int r = (int)(y >> 17);
        csr[offs[d] + r] = s;
    }
}

__global__ void scan1(const int* __restrict__ counts, int* __restrict__ offs,
                      int* __restrict__ bsum, int N) {
    __shared__ int tmp[256];
    int t = threadIdx.x;
    int i = blockIdx.x * 256 + t;
    int v = (i < N) ? counts[i] : 0;
    tmp[t] = v;
    __syncthreads();
    for (int d = 1; d < 256; d <<= 1) {
        int add = (t >= d) ? tmp[t - d] : 0;
        __syncthreads();
        tmp[t] += add;
        __syncthreads();
    }
    if (i < N) offs[i] = tmp[t] - v;
    if (t == 255) bsum[blockIdx.x] = tmp[255];
}

__global__ void scan2(int* __restrict__ bsum, int nb) {
    __shared__ int tmp[512];
    int t = threadIdx.x;
    int v = (t < nb) ? bsum[t] : 0;
    tmp[t] = v;
    __syncthreads();
    for (int d = 1; d < 512; d <<= 1) {
        int add = (t >= d) ? tmp[t - d] : 0;
        __syncthreads();
        tmp[t] += add;
        __syncthreads();
    }
    if (t < nb) bsum[t] = tmp[t] - v;
}

__global__ void scan3(int* __restrict__ offs, const int* __restrict__ bsum,
                      const int* __restrict__ counts, float* __restrict__ inv,
                      int N, int E) {
    int i = blockIdx.x * 256 + threadIdx.x;
    if (i < N) {
        offs[i] += bsum[blockIdx.x];
        inv[i] = 1.0f / (float)(counts[i] + 1);
    }
    if (i == 0) offs[N] = E;
}

// ---------------- weight pack: W[128x128] fp32 -> MFMA B-fragment order bf16 ----------------

__global__ void pack_w(const float* __restrict__ W, ushort16* __restrict__ Wp) {
    int b = blockIdx.x;      // 0..31 = nt*4 + ks
    int lane = threadIdx.x;  // 64
    int nt = b >> 2, ks = b & 3;
    int n = nt * 16 + (lane & 15);
    int kbase = ks * 32 + ((lane >> 4) << 3);
    ushort16 tmp[8];
#pragma unroll
    for (int i = 0; i < 8; i++) tmp[i] = f2b(W[(size_t)(kbase + i) * HID + n]);
    *(uint4*)&Wp[((size_t)b * 64 + lane) * 8] = *(uint4*)tmp;
}

// ---------------- MFMA GEMM: Z(sliced [8][N][16] bf16) = A @ W ----------------
// A: AF32 ? dense fp32 [N][128] : sliced bf16 [8][N][16]

template <int AF32>
__global__ __launch_bounds__(256) void gemm_mfma(const void* __restrict__ Av,
                                                 const ushort16* __restrict__ Wp,
                                                 ushort16* __restrict__ Z, int M) {
    __shared__ __align__(16) ushort16 Wl[32 * 64 * 8];  // 32 KB
    int t = threadIdx.x;
    const uint4* wp4 = (const uint4*)Wp;
    uint4* wl4 = (uint4*)Wl;
#pragma unroll
    for (int p = 0; p < 8; p++) wl4[t + p * 256] = wp4[t + p * 256];
    __syncthreads();

    int wv = t >> 6, lane = t & 63;
    int row = blockIdx.x * 64 + wv * 16 + (lane & 15);
    int rowc = min(row, M - 1);
    int kb = (lane >> 4) << 3;  // 0,8,16,24

    short8 a[4];
    if (AF32) {
        const float* A = (const float*)Av;
#pragma unroll
        for (int ks = 0; ks < 4; ks++) {
            const float* p = A + (size_t)rowc * HID + ks * 32 + kb;
            floatx4 lo = *(const floatx4*)p;
            floatx4 hi = *(const floatx4*)(p + 4);
            union { short8 s; ushort16 u[8]; } cv;
            cv.u[0] = f2b(lo.x); cv.u[1] = f2b(lo.y); cv.u[2] = f2b(lo.z); cv.u[3] = f2b(lo.w);
            cv.u[4] = f2b(hi.x); cv.u[5] = f2b(hi.y); cv.u[6] = f2b(hi.z); cv.u[7] = f2b(hi.w);
            a[ks] = cv.s;
        }
    } else {
        const ushort16* A = (const ushort16*)Av;
        int sl = kb >> 4, soff = kb & 8;
#pragma unroll
        for (int ks = 0; ks < 4; ks++) {
            int slice = ks * 2 + sl;
            a[ks] = *(const short8*)(A + ((size_t)slice * NNODES + rowc) * 16 + soff);
        }
    }

    floatx4 acc[8];
#pragma unroll
    for (int nt = 0; nt < 8; nt++) acc[nt] = (floatx4){0.f, 0.f, 0.f, 0.f};

#pragma unroll
    for (int nt = 0; nt < 8; nt++) {
#pragma unroll
        for (int ks = 0; ks < 4; ks++) {
            short8 b = *(const short8*)&Wl[(size_t)(((nt << 2) | ks) * 64 + lane) * 8];
            acc[nt] = __builtin_amdgcn_mfma_f32_16x16x32_bf16(a[ks], b, acc[nt], 0, 0, 0);
        }
    }

    int orow = blockIdx.x * 64 + wv * 16 + ((lane >> 4) << 2);
    int col = lane & 15;
#pragma unroll
    for (int i = 0; i < 4; i++) {
        int r = orow + i;
        if (r < M) {
#pragma unroll
            for (int nt = 0; nt < 8; nt++)
                Z[((size_t)nt * NNODES + r) * 16 + col] = f2b(acc[nt][i]);
        }
    }
}

// ---------------- sliced aggregate: slice = blockIdx%8 (pinned to its XCD's L2) ----------------
// Z,H sliced [8][N][8] uint32 (16 bf16). 8 lanes per node; loads batched 8-deep
// (issue all 8 gathers into a[], THEN accumulate — no per-edge waitcnt).

__global__ __launch_bounds__(256) void agg_sliced(const uint32* __restrict__ Z,
                                                  const int* __restrict__ offs,
                                                  const int* __restrict__ csr,
                                                  const float* __restrict__ inv,
                                                  const float* __restrict__ bias,
                                                  uint32* __restrict__ H, int N) {
    int s = blockIdx.x & 7;
    int chunk = blockIdx.x >> 3;
    int t = threadIdx.x;
    int grp = t >> 3;            // 0..31 node-group
    int l4 = t & 7;              // feature-pair index
    int lanebase = t & 56;       // group base within wave
    const uint32* Zs = Z + (size_t)s * NNODES * 8;
    uint32* Hs = H + (size_t)s * NNODES * 8;
    float2 bb = ((const float2*)(bias + s * 16))[l4];
#pragma unroll
    for (int it = 0; it < AGG_BN / 32; ++it) {
        int v = chunk * AGG_BN + it * 32 + grp;
        bool act = v < N;
        float ax = 0.f, ay = 0.f, iv = 0.f;
        int beg = 0, cnt = 0;
        if (act) {
            uint32 sv = Zs[(size_t)v * 8 + l4];
            ax = blo(sv); ay = bhi(sv);
            beg = offs[v];
            cnt = offs[v + 1] - beg;
            iv = inv[v];
        }
        int j = 0;
        for (; j + 8 <= cnt; j += 8) {
            int idxr = __builtin_nontemporal_load(&csr[beg + j + l4]);
            uint32 a[8];
#pragma unroll
            for (int q = 0; q < 8; q++) {
                int u = __shfl(idxr, lanebase + q, 64);
                a[q] = Zs[(size_t)u * 8 + l4];
            }
#pragma unroll
            for (int q = 0; q < 8; q++) { ax += blo(a[q]); ay += bhi(a[q]); }
        }
        int rem = cnt - j;
        if (rem > 0) {
            int idxr = __builtin_nontemporal_load(&csr[beg + j + min(l4, rem - 1)]);
            uint32 a[8];
#pragma unroll
            for (int q = 0; q < 8; q++) {
                int u = __shfl(idxr, lanebase + min(q, rem - 1), 64);
                a[q] = Zs[(size_t)u * 8 + l4];
            }
#pragma unroll
            for (int q = 0; q < 8; q++) {
                if (q < rem) { ax += blo(a[q]); ay += bhi(a[q]); }
            }
        }
        if (act) {
            float rx = fmaxf(ax * iv + bb.x, 0.f);
            float ry = fmaxf(ay * iv + bb.y, 0.f);
            __builtin_nontemporal_store(pack2(rx, ry), &Hs[(size_t)v * 8 + l4]);
        }
    }
}

// ---------------- layer 5: Z16[N][16] bf16 = H(sliced) @ W5 ----------------

__global__ __launch_bounds__(256) void gemm16(const uint32* __restrict__ A,  // sliced [8][N][8]
                                              const float* __restrict__ W5,
                                              uint32* __restrict__ Z16, int M) {
    __shared__ float Ws[HID * OUTF];  // 8 KB
    int t = threadIdx.x;
    for (int i = t; i < HID * OUTF; i += 256) Ws[i] = W5[i];
    __syncthreads();
    int gid = blockIdx.x * 256 + t;
    int r = gid >> 3, cp = gid & 7;
    if (r >= M) return;
    float a0 = 0.f, a1 = 0.f;
#pragma unroll
    for (int s8 = 0; s8 < 8; s8++) {
        const uint32* ar = A + ((size_t)s8 * NNODES + r) * 8;
#pragma unroll
        for (int k = 0; k < 8; k++) {
            uint32 u = ar[k];
            float f0 = blo(u), f1 = bhi(u);
            a0 += f0 * Ws[(s8 * 16 + 2 * k) * OUTF + 2 * cp] +
                  f1 * Ws[(s8 * 16 + 2 * k + 1) * OUTF + 2 * cp];
            a1 += f0 * Ws[(s8 * 16 + 2 * k) * OUTF + 2 * cp + 1] +
                  f1 * Ws[(s8 * 16 + 2 * k + 1) * OUTF + 2 * cp + 1];
        }
    }
    Z16[(size_t)r * 8 + cp] = pack2(a0, a1);
}

// ---------------- layer 5 aggregate + bias + log_softmax (8 lanes/node, batched) ----------------

__global__ __launch_bounds__(256) void agg16_lsm(const uint32* __restrict__ Z16,
                                                 const int* __restrict__ offs,
                                                 const int* __restrict__ csr,
                                                 const float* __restrict__ inv,
                                                 const float* __restrict__ b5,
                                                 float* __restrict__ out, int N) {
    int gid = blockIdx.x * 256 + threadIdx.x;
    int v = gid >> 3, l = gid & 7;
    if (v >= N) return;
    int lanebase = threadIdx.x & 56;
    uint32 sv = Z16[(size_t)v * 8 + l];
    float ax = blo(sv), ay = bhi(sv);
    int beg = offs[v], cnt = offs[v + 1] - beg;
    int j = 0;
    for (; j + 8 <= cnt; j += 8) {
        int idxr = __builtin_nontemporal_load(&csr[beg + j + l]);
        uint32 a[8];
#pragma unroll
        for (int q = 0; q < 8; q++) {
            int u = __shfl(idxr, lanebase + q, 64);
            a[q] = Z16[(size_t)u * 8 + l];
        }
#pragma unroll
        for (int q = 0; q < 8; q++) { ax += blo(a[q]); ay += bhi(a[q]); }
    }
    int rem = cnt - j;
    if (rem > 0) {
        int idxr = __builtin_nontemporal_load(&csr[beg + j + min(l, rem - 1)]);
        uint32 a[8];
#pragma unroll
        for (int q = 0; q < 8; q++) {
            int u = __shfl(idxr, lanebase + min(q, rem - 1), 64);
            a[q] = Z16[(size_t)u * 8 + l];
        }
#pragma unroll
        for (int q = 0; q < 8; q++) {
            if (q < rem) { ax += blo(a[q]); ay += bhi(a[q]); }
        }
    }
    float iv = inv[v];
    float2 bb = *(const float2*)(b5 + 2 * l);
    float vx = ax * iv + bb.x, vy = ay * iv + bb.y;
    float mm = fmaxf(vx, vy);
#pragma unroll
    for (int d = 1; d < 8; d <<= 1) mm = fmaxf(mm, __shfl_xor(mm, d, 8));
    float ex = expf(vx - mm), ey = expf(vy - mm);
    float ss = ex + ey;
#pragma unroll
    for (int d = 1; d < 8; d <<= 1) ss += __shfl_xor(ss, d, 8);
    float ls = logf(ss);
    *(float2*)&out[(size_t)v * OUTF + 2 * l] = make_float2(vx - mm - ls, vy - mm - ls);
}

// ---------------- launch ----------------

extern "C" void kernel_launch(void* const* d_in, const int* in_sizes, int n_in,
                              void* d_out, int out_size, void* d_ws, size_t ws_size,
                              hipStream_t stream) {
    const float* x   = (const float*)d_in[0];
    const int*   src = (const int*)d_in[1];
    const int*   dst = (const int*)d_in[2];
    const float* W1 = (const float*)d_in[3];
    const float* b1 = (const float*)d_in[4];
    const float* W2 = (const float*)d_in[5];
    const float* b2 = (const float*)d_in[6];
    const float* W3 = (const float*)d_in[7];
    const float* b3 = (const float*)d_in[8];
    const float* W4 = (const float*)d_in[9];
    const float* b4 = (const float*)d_in[10];
    const float* W5 = (const float*)d_in[11];
    const float* b5 = (const float*)d_in[12];

    char* ws = (char*)d_ws;
    size_t off = 0;
    auto alloc = [&](size_t bytes) {
        void* p = ws + off;
        off = (off + bytes + 255) & ~(size_t)255;
        return p;
    };
    ushort16* zb   = (ushort16*)alloc((size_t)NNODES * HID * 2);
    ushort16* hb   = (ushort16*)alloc((size_t)NNODES * HID * 2);
    uint32*   z16b = (uint32*)alloc((size_t)NNODES * OUTF * 2);
    int*      counts = (int*)alloc((size_t)NNODES * 4);
    int*      offs   = (int*)alloc((size_t)(NNODES + 1) * 4);
    int*      bsum   = (int*)alloc(512 * 4);
    int*      csr    = (int*)alloc((size_t)NEDGES * 4);
    float*    invd   = (float*)alloc((size_t)NNODES * 4);
    ull*      stage  = (ull*)alloc((size_t)NB * BCAP * 8);
    int*      bcursor = (int*)alloc(NB * 4);
    ushort16* Wp1 = (ushort16*)alloc((size_t)HID * HID * 2);
    ushort16* Wp2 = (ushort16*)alloc((size_t)HID * HID * 2);
    ushort16* Wp3 = (ushort16*)alloc((size_t)HID * HID * 2);
    ushort16* Wp4 = (ushort16*)alloc((size_t)HID * HID * 2);
    (void)ws_size; (void)in_sizes; (void)n_in; (void)out_size;

    const int N = NNODES, E = NEDGES;
    int nb = (N + 255) / 256;

    // CSR build
    hipMemsetAsync(counts, 0, (size_t)N * 4, stream);
    hipMemsetAsync(bcursor, 0, NB * 4, stream);
    bucketize<<<(E + BZT - 1) / BZT, BZT, 0, stream>>>(src, dst, counts, bcursor, stage, E);
    scan1<<<nb, 256, 0, stream>>>(counts, offs, bsum, N);
    scan2<<<1, 512, 0, stream>>>(bsum, nb);
    scan3<<<nb, 256, 0, stream>>>(offs, bsum, counts, invd, N, E);
    fill2<<<NB * KB, 256, 0, stream>>>(stage, bcursor, offs, csr);

    // pack weights
    pack_w<<<32, 64, 0, stream>>>(W1, Wp1);
    pack_w<<<32, 64, 0, stream>>>(W2, Wp2);
    pack_w<<<32, 64, 0, stream>>>(W3, Wp3);
    pack_w<<<32, 64, 0, stream>>>(W4, Wp4);

    int gemmGrid = (N + 63) / 64;
    int aggGrid  = 8 * ((N + AGG_BN - 1) / AGG_BN);

    gemm_mfma<1><<<gemmGrid, 256, 0, stream>>>((const void*)x, Wp1, zb, N);
    agg_sliced<<<aggGrid, 256, 0, stream>>>((const uint32*)zb, offs, csr, invd, b1, (uint32*)hb, N);

    gemm_mfma<0><<<gemmGrid, 256, 0, stream>>>((const void*)hb, Wp2, zb, N);
    agg_sliced<<<aggGrid, 256, 0, stream>>>((const uint32*)zb, offs, csr, invd, b2, (uint32*)hb, N);

    gemm_mfma<0><<<gemmGrid, 256, 0, stream>>>((const void*)hb, Wp3, zb, N);
    agg_sliced<<<aggGrid, 256, 0, stream>>>((const uint32*)zb, offs, csr, invd, b3, (uint32*)hb, N);

    gemm_mfma<0><<<gemmGrid, 256, 0, stream>>>((const void*)hb, Wp4, zb, N);
    agg_sliced<<<aggGrid, 256, 0, stream>>>((const uint32*)zb, offs, csr, invd, b4, (uint32*)hb, N);

    gemm16<<<(N * 8 + 255) / 256, 256, 0, stream>>>((const uint32*)hb, W5, z16b, N);
    agg16_lsm<<<(N * 8 + 255) / 256, 256, 0, stream>>>(z16b, offs, csr, invd, b5,
                                                       (float*)d_out, N);
}

// Round 7
// 386.729 us; speedup vs baseline: 1.6470x; 1.3080x over previous
//
#include <hip/hip_runtime.h>
#include <hip/hip_bf16.h>

#define NNODES 100000
#define NEDGES 1000000
#define HID 128
#define OUTF 16
#define NB 16       // dst-range buckets for CSR build
#define BCAP 81920  // per-bucket stage capacity (expected ~62500)
#define KB 64       // blocks per bucket in fill2
#define BZT 1024    // bucketize block size

typedef __attribute__((ext_vector_type(8))) short short8;
typedef __attribute__((ext_vector_type(4))) float floatx4;
typedef __attribute__((ext_vector_type(4))) unsigned int uintx4;
typedef unsigned int uint32;
typedef unsigned long long ull;
typedef unsigned short ushort16;

__device__ __forceinline__ float blo(uint32 u) { return __uint_as_float(u << 16); }
__device__ __forceinline__ float bhi(uint32 u) { return __uint_as_float(u & 0xffff0000u); }
__device__ __forceinline__ ushort16 f2b(float f) {
    __hip_bfloat16 h = __float2bfloat16(f);
    return *reinterpret_cast<ushort16*>(&h);
}
__device__ __forceinline__ uint32 pack2(float a, float b) {
    return (uint32)f2b(a) | ((uint32)f2b(b) << 16);
}

// ---------------- CSR build ----------------
// Pass A: histogram (atomic returns per-node rank) + LDS-reordered bucket compaction.
// Staged word: lo32 = src, hi32 = dst | (rank<<17).

__global__ __launch_bounds__(BZT) void bucketize(const int* __restrict__ src,
                                                 const int* __restrict__ dst,
                                                 int* __restrict__ counts,
                                                 int* __restrict__ bcursor,
                                                 ull* __restrict__ stage, int E) {
    __shared__ int cnt[NB], lbase[NB], gbase[NB];
    __shared__ int2 buf[BZT];
    __shared__ unsigned char bb[BZT];
    int t = threadIdx.x;
    int e0 = blockIdx.x * BZT;
    int e = e0 + t;
    if (t < NB) cnt[t] = 0;
    __syncthreads();
    int s = 0; unsigned y = 0; int b = 0, r = 0;
    bool valid = e < E;
    if (valid) {
        s = src[e];
        int d = dst[e];
        int rk = atomicAdd(&counts[d], 1);        // per-node rank (also the histogram)
        y = (unsigned)d | ((unsigned)rk << 17);
        b = (int)((unsigned)d * NB / NNODES);
        r = atomicAdd(&cnt[b], 1);
    }
    __syncthreads();
    if (t == 0) {
        int run = 0;
        for (int i = 0; i < NB; i++) { lbase[i] = run; run += cnt[i]; }
    }
    __syncthreads();
    if (valid) {
        int p = lbase[b] + r;
        buf[p] = make_int2(s, (int)y);
        bb[p] = (unsigned char)b;
    }
    if (t < NB) gbase[t] = atomicAdd(&bcursor[t], cnt[t]);
    __syncthreads();
    int nvalid = min(BZT, E - e0);
    if (t < nvalid) {
        int b2 = bb[t];
        int2 sd = buf[t];
        int pos = gbase[b2] + (t - lbase[b2]);
        if (pos < BCAP) {
            ull val = (ull)(unsigned)sd.x | ((ull)(unsigned)sd.y << 32);
            __builtin_nontemporal_store(val, &stage[(size_t)b2 * BCAP + pos]);
        }
    }
}

// Pass B: atomic-free scatter within one bucket's csr window; buckets pinned to XCDs.
__global__ __launch_bounds__(256) void fill2(const ull* __restrict__ stage,
                                             const int* __restrict__ bcursor,
                                             const int* __restrict__ offs,
                                             int* __restrict__ csr) {
    int blk = blockIdx.x;
    int b = (blk & 7) + 8 * ((blk >> 3) & 1);  // home XCD = b%8
    int slot = blk >> 4;
    int cntb = min(bcursor[b], BCAP);
    int per = (cntb + KB - 1) / KB;
    int s0 = slot * per;
    int s1 = min(s0 + per, cntb);
    const ull* st = stage + (size_t)b * BCAP;
    for (int i = s0 + threadIdx.x; i < s1; i += 256) {
        ull v = __builtin_nontemporal_load(&st[i]);
        int s = (int)(v & 0xffffffffu);
        unsigned y = (unsigned)(v >> 32);
        int d = (int)(y & 0x1ffffu);
        int r = (int)(y >> 17);
        csr[offs[d] + r] = s;
    }
}

// scan of PADDED counts (pad4) -> offs are multiples of 4 (aligned int4 csr reads)
__global__ void scan1(const int* __restrict__ counts, int* __restrict__ offs,
                      int* __restrict__ bsum, int N) {
    __shared__ int tmp[256];
    int t = threadIdx.x;
    int i = blockIdx.x * 256 + t;
    int v = (i < N) ? ((counts[i] + 3) & ~3) : 0;
    tmp[t] = v;
    __syncthreads();
    for (int d = 1; d < 256; d <<= 1) {
        int add = (t >= d) ? tmp[t - d] : 0;
        __syncthreads();
        tmp[t] += add;
        __syncthreads();
    }
    if (i < N) offs[i] = tmp[t] - v;
    if (t == 255) bsum[blockIdx.x] = tmp[255];
}

__global__ void scan2(int* __restrict__ bsum, int nb) {
    __shared__ int tmp[512];
    int t = threadIdx.x;
    int v = (t < nb) ? bsum[t] : 0;
    tmp[t] = v;
    __syncthreads();
    for (int d = 1; d < 512; d <<= 1) {
        int add = (t >= d) ? tmp[t - d] : 0;
        __syncthreads();
        tmp[t] += add;
        __syncthreads();
    }
    if (t < nb) bsum[t] = tmp[t] - v;
}

__global__ void scan3(int* __restrict__ offs, const int* __restrict__ bsum,
                      const int* __restrict__ counts, float* __restrict__ inv,
                      int N) {
    int i = blockIdx.x * 256 + threadIdx.x;
    if (i < N) {
        offs[i] += bsum[blockIdx.x];
        inv[i] = 1.0f / (float)(counts[i] + 1);
    }
}

// ---------------- weight pack: W[128x128] fp32 -> MFMA B-fragment order bf16 ----------------

__global__ void pack_w(const float* __restrict__ W, ushort16* __restrict__ Wp) {
    int b = blockIdx.x;      // 0..31 = nt*4 + ks
    int lane = threadIdx.x;  // 64
    int nt = b >> 2, ks = b & 3;
    int n = nt * 16 + (lane & 15);
    int kbase = ks * 32 + ((lane >> 4) << 3);
    ushort16 tmp[8];
#pragma unroll
    for (int i = 0; i < 8; i++) tmp[i] = f2b(W[(size_t)(kbase + i) * HID + n]);
    *(uint4*)&Wp[((size_t)b * 64 + lane) * 8] = *(uint4*)tmp;
}

// ---------------- MFMA GEMM: Z(sliced [8][N][16] bf16) = A @ W ----------------
// A: AF32 ? dense fp32 [N][128] : sliced bf16 [8][N][16]

template <int AF32>
__global__ __launch_bounds__(256) void gemm_mfma(const void* __restrict__ Av,
                                                 const ushort16* __restrict__ Wp,
                                                 ushort16* __restrict__ Z, int M) {
    __shared__ __align__(16) ushort16 Wl[32 * 64 * 8];  // 32 KB
    int t = threadIdx.x;
    const uint4* wp4 = (const uint4*)Wp;
    uint4* wl4 = (uint4*)Wl;
#pragma unroll
    for (int p = 0; p < 8; p++) wl4[t + p * 256] = wp4[t + p * 256];
    __syncthreads();

    int wv = t >> 6, lane = t & 63;
    int row = blockIdx.x * 64 + wv * 16 + (lane & 15);
    int rowc = min(row, M - 1);
    int kb = (lane >> 4) << 3;  // 0,8,16,24

    short8 a[4];
    if (AF32) {
        const float* A = (const float*)Av;
#pragma unroll
        for (int ks = 0; ks < 4; ks++) {
            const float* p = A + (size_t)rowc * HID + ks * 32 + kb;
            floatx4 lo = *(const floatx4*)p;
            floatx4 hi = *(const floatx4*)(p + 4);
            union { short8 s; ushort16 u[8]; } cv;
            cv.u[0] = f2b(lo.x); cv.u[1] = f2b(lo.y); cv.u[2] = f2b(lo.z); cv.u[3] = f2b(lo.w);
            cv.u[4] = f2b(hi.x); cv.u[5] = f2b(hi.y); cv.u[6] = f2b(hi.z); cv.u[7] = f2b(hi.w);
            a[ks] = cv.s;
        }
    } else {
        const ushort16* A = (const ushort16*)Av;
        int sl = kb >> 4, soff = kb & 8;
#pragma unroll
        for (int ks = 0; ks < 4; ks++) {
            int slice = ks * 2 + sl;
            a[ks] = *(const short8*)(A + ((size_t)slice * NNODES + rowc) * 16 + soff);
        }
    }

    floatx4 acc[8];
#pragma unroll
    for (int nt = 0; nt < 8; nt++) acc[nt] = (floatx4){0.f, 0.f, 0.f, 0.f};

#pragma unroll
    for (int nt = 0; nt < 8; nt++) {
#pragma unroll
        for (int ks = 0; ks < 4; ks++) {
            short8 b = *(const short8*)&Wl[(size_t)(((nt << 2) | ks) * 64 + lane) * 8];
            acc[nt] = __builtin_amdgcn_mfma_f32_16x16x32_bf16(a[ks], b, acc[nt], 0, 0, 0);
        }
    }

    int orow = blockIdx.x * 64 + wv * 16 + ((lane >> 4) << 2);
    int col = lane & 15;
#pragma unroll
    for (int i = 0; i < 4; i++) {
        int r = orow + i;
        if (r < M) {
#pragma unroll
            for (int nt = 0; nt < 8; nt++)
                Z[((size_t)nt * NNODES + r) * 16 + col] = f2b(acc[nt][i]);
        }
    }
}

// ---------------- sliced aggregate v2: 2 lanes/node, 16 B loads ----------------
// Z,H sliced [8][N][8 uint32] (32 B/node-slice). slice = blockIdx&7 -> home XCD.
// Per pair: csr read as aligned int4 (8 idx / pair / batch), gathers are uint4.

#define ACC4(g)                                        \
    {                                                  \
        acc0.x += blo((g).x); acc0.y += bhi((g).x);    \
        acc1.x += blo((g).y); acc1.y += bhi((g).y);    \
        acc2.x += blo((g).z); acc2.y += bhi((g).z);    \
        acc3.x += blo((g).w); acc3.y += bhi((g).w);    \
    }

__global__ __launch_bounds__(256) void agg_sliced(const uint32* __restrict__ Z,
                                                  const int* __restrict__ offs,
                                                  const int* __restrict__ counts,
                                                  const int* __restrict__ csr,
                                                  const float* __restrict__ inv,
                                                  const float* __restrict__ bias,
                                                  uint32* __restrict__ H, int N) {
    int s = blockIdx.x & 7;
    int chunk = blockIdx.x >> 3;
    int t = threadIdx.x;
    int l = t & 1;                 // which 16 B half of the 32 B row
    int v = chunk * 128 + (t >> 1);
    int pairbase = t & 62;         // lane index of half-0 within the wave
    bool act = v < N;
    int vc = act ? v : N - 1;
    const uint4* Zs = (const uint4*)(Z + (size_t)s * NNODES * 8);
    uint4* Hs = (uint4*)(H + (size_t)s * NNODES * 8);

    uint4 sv = Zs[(size_t)vc * 2 + l];
    float2 acc0 = make_float2(blo(sv.x), bhi(sv.x));
    float2 acc1 = make_float2(blo(sv.y), bhi(sv.y));
    float2 acc2 = make_float2(blo(sv.z), bhi(sv.z));
    float2 acc3 = make_float2(blo(sv.w), bhi(sv.w));

    int beg = offs[vc];
    int cnt = act ? counts[vc] : 0;
    int j = 0;
    for (; j + 8 <= cnt; j += 8) {
        int4 iv = *(const int4*)&csr[beg + j + 4 * l];
        uint4 g[8];
#pragma unroll
        for (int q = 0; q < 8; q++) {
            int c = (q & 3) == 0 ? iv.x : (q & 3) == 1 ? iv.y : (q & 3) == 2 ? iv.z : iv.w;
            int u = __shfl(c, pairbase + (q >> 2), 64);
            g[q] = Zs[(size_t)u * 2 + l];
        }
#pragma unroll
        for (int q = 0; q < 8; q++) ACC4(g[q]);
    }
    int rem = cnt - j;
    if (rem > 0) {
        // padded csr (+ slack, memset 0) makes these loads safe; pads gather node 0,
        // masked out at accumulate time.
        int4 iv = *(const int4*)&csr[beg + j + 4 * l];
        uint4 g[8];
#pragma unroll
        for (int q = 0; q < 8; q++) {
            int c = (q & 3) == 0 ? iv.x : (q & 3) == 1 ? iv.y : (q & 3) == 2 ? iv.z : iv.w;
            int u = __shfl(c, pairbase + (q >> 2), 64);
            g[q] = Zs[(size_t)u * 2 + l];
        }
#pragma unroll
        for (int q = 0; q < 8; q++) {
            if (q < rem) ACC4(g[q]);
        }
    }

    float sc = inv[vc];
    const float* bp = bias + s * 16 + l * 8;
    floatx4 b01 = *(const floatx4*)bp;
    floatx4 b23 = *(const floatx4*)(bp + 4);
    uintx4 o;
    o.x = pack2(fmaxf(acc0.x * sc + b01.x, 0.f), fmaxf(acc0.y * sc + b01.y, 0.f));
    o.y = pack2(fmaxf(acc1.x * sc + b01.z, 0.f), fmaxf(acc1.y * sc + b01.w, 0.f));
    o.z = pack2(fmaxf(acc2.x * sc + b23.x, 0.f), fmaxf(acc2.y * sc + b23.y, 0.f));
    o.w = pack2(fmaxf(acc3.x * sc + b23.z, 0.f), fmaxf(acc3.y * sc + b23.w, 0.f));
    if (act) __builtin_nontemporal_store(o, (uintx4*)&Hs[(size_t)v * 2 + l]);
}

// ---------------- layer 5: Z16[N][16] bf16 = H(sliced) @ W5 ----------------

__global__ __launch_bounds__(256) void gemm16(const uint32* __restrict__ A,  // sliced [8][N][8]
                                              const float* __restrict__ W5,
                                              uint32* __restrict__ Z16, int M) {
    __shared__ float Ws[HID * OUTF];  // 8 KB
    int t = threadIdx.x;
    for (int i = t; i < HID * OUTF; i += 256) Ws[i] = W5[i];
    __syncthreads();
    int gid = blockIdx.x * 256 + t;
    int r = gid >> 3, cp = gid & 7;
    if (r >= M) return;
    float a0 = 0.f, a1 = 0.f;
#pragma unroll
    for (int s8 = 0; s8 < 8; s8++) {
        const uint32* ar = A + ((size_t)s8 * NNODES + r) * 8;
#pragma unroll
        for (int k = 0; k < 8; k++) {
            uint32 u = ar[k];
            float f0 = blo(u), f1 = bhi(u);
            a0 += f0 * Ws[(s8 * 16 + 2 * k) * OUTF + 2 * cp] +
                  f1 * Ws[(s8 * 16 + 2 * k + 1) * OUTF + 2 * cp];
            a1 += f0 * Ws[(s8 * 16 + 2 * k) * OUTF + 2 * cp + 1] +
                  f1 * Ws[(s8 * 16 + 2 * k + 1) * OUTF + 2 * cp + 1];
        }
    }
    Z16[(size_t)r * 8 + cp] = pack2(a0, a1);
}

// ---------------- layer 5 aggregate + bias + log_softmax (2 lanes/node) ----------------

__global__ __launch_bounds__(256) void agg16_lsm(const uint32* __restrict__ Z16,
                                                 const int* __restrict__ offs,
                                                 const int* __restrict__ counts,
                                                 const int* __restrict__ csr,
                                                 const float* __restrict__ inv,
                                                 const float* __restrict__ b5,
                                                 float* __restrict__ out, int N) {
    int t = threadIdx.x;
    int l = t & 1;
    int v = blockIdx.x * 128 + (t >> 1);
    int pairbase = t & 62;
    bool act = v < N;
    int vc = act ? v : N - 1;
    const uint4* Zs = (const uint4*)Z16;

    uint4 sv = Zs[(size_t)vc * 2 + l];
    float2 acc0 = make_float2(blo(sv.x), bhi(sv.x));
    float2 acc1 = make_float2(blo(sv.y), bhi(sv.y));
    float2 acc2 = make_float2(blo(sv.z), bhi(sv.z));
    float2 acc3 = make_float2(blo(sv.w), bhi(sv.w));

    int beg = offs[vc];
    int cnt = act ? counts[vc] : 0;
    int j = 0;
    for (; j + 8 <= cnt; j += 8) {
        int4 iv = *(const int4*)&csr[beg + j + 4 * l];
        uint4 g[8];
#pragma unroll
        for (int q = 0; q < 8; q++) {
            int c = (q & 3) == 0 ? iv.x : (q & 3) == 1 ? iv.y : (q & 3) == 2 ? iv.z : iv.w;
            int u = __shfl(c, pairbase + (q >> 2), 64);
            g[q] = Zs[(size_t)u * 2 + l];
        }
#pragma unroll
        for (int q = 0; q < 8; q++) ACC4(g[q]);
    }
    int rem = cnt - j;
    if (rem > 0) {
        int4 iv = *(const int4*)&csr[beg + j + 4 * l];
        uint4 g[8];
#pragma unroll
        for (int q = 0; q < 8; q++) {
            int c = (q & 3) == 0 ? iv.x : (q & 3) == 1 ? iv.y : (q & 3) == 2 ? iv.z : iv.w;
            int u = __shfl(c, pairbase + (q >> 2), 64);
            g[q] = Zs[(size_t)u * 2 + l];
        }
#pragma unroll
        for (int q = 0; q < 8; q++) {
            if (q < rem) ACC4(g[q]);
        }
    }

    float sc = inv[vc];
    const float* bp = b5 + l * 8;
    floatx4 b01 = *(const floatx4*)bp;
    floatx4 b23 = *(const floatx4*)(bp + 4);
    float val[8];
    val[0] = acc0.x * sc + b01.x; val[1] = acc0.y * sc + b01.y;
    val[2] = acc1.x * sc + b01.z; val[3] = acc1.y * sc + b01.w;
    val[4] = acc2.x * sc + b23.x; val[5] = acc2.y * sc + b23.y;
    val[6] = acc3.x * sc + b23.z; val[7] = acc3.y * sc + b23.w;
    float mm = val[0];
#pragma unroll
    for (int k = 1; k < 8; k++) mm = fmaxf(mm, val[k]);
    mm = fmaxf(mm, __shfl_xor(mm, 1, 64));
    float ss = 0.f;
#pragma unroll
    for (int k = 0; k < 8; k++) ss += expf(val[k] - mm);
    ss += __shfl_xor(ss, 1, 64);
    float ls = mm + logf(ss);
    if (act) {
        float4 o0 = make_float4(val[0] - ls, val[1] - ls, val[2] - ls, val[3] - ls);
        float4 o1 = make_float4(val[4] - ls, val[5] - ls, val[6] - ls, val[7] - ls);
        float* op = out + (size_t)v * OUTF + l * 8;
        *(float4*)op = o0;
        *(float4*)(op + 4) = o1;
    }
}

// ---------------- launch ----------------

extern "C" void kernel_launch(void* const* d_in, const int* in_sizes, int n_in,
                              void* d_out, int out_size, void* d_ws, size_t ws_size,
                              hipStream_t stream) {
    const float* x   = (const float*)d_in[0];
    const int*   src = (const int*)d_in[1];
    const int*   dst = (const int*)d_in[2];
    const float* W1 = (const float*)d_in[3];
    const float* b1 = (const float*)d_in[4];
    const float* W2 = (const float*)d_in[5];
    const float* b2 = (const float*)d_in[6];
    const float* W3 = (const float*)d_in[7];
    const float* b3 = (const float*)d_in[8];
    const float* W4 = (const float*)d_in[9];
    const float* b4 = (const float*)d_in[10];
    const float* W5 = (const float*)d_in[11];
    const float* b5 = (const float*)d_in[12];

    char* ws = (char*)d_ws;
    size_t off = 0;
    auto alloc = [&](size_t bytes) {
        void* p = ws + off;
        off = (off + bytes + 255) & ~(size_t)255;
        return p;
    };
    const size_t CSR_ELEMS = (size_t)NEDGES + 3 * (size_t)NNODES + 64;  // padded + slack
    ushort16* zb   = (ushort16*)alloc((size_t)NNODES * HID * 2);
    ushort16* hb   = (ushort16*)alloc((size_t)NNODES * HID * 2);
    uint32*   z16b = (uint32*)alloc((size_t)NNODES * OUTF * 2);
    int*      counts = (int*)alloc((size_t)NNODES * 4);
    int*      offs   = (int*)alloc((size_t)(NNODES + 1) * 4);
    int*      bsum   = (int*)alloc(512 * 4);
    int*      csr    = (int*)alloc(CSR_ELEMS * 4);
    float*    invd   = (float*)alloc((size_t)NNODES * 4);
    ull*      stage  = (ull*)alloc((size_t)NB * BCAP * 8);
    int*      bcursor = (int*)alloc(NB * 4);
    ushort16* Wp1 = (ushort16*)alloc((size_t)HID * HID * 2);
    ushort16* Wp2 = (ushort16*)alloc((size_t)HID * HID * 2);
    ushort16* Wp3 = (ushort16*)alloc((size_t)HID * HID * 2);
    ushort16* Wp4 = (ushort16*)alloc((size_t)HID * HID * 2);
    (void)ws_size; (void)in_sizes; (void)n_in; (void)out_size;

    const int N = NNODES, E = NEDGES;
    int nb = (N + 255) / 256;

    // CSR build
    hipMemsetAsync(counts, 0, (size_t)N * 4, stream);
    hipMemsetAsync(bcursor, 0, NB * 4, stream);
    hipMemsetAsync(csr, 0, CSR_ELEMS * 4, stream);  // pad entries -> node 0 (masked)
    bucketize<<<(E + BZT - 1) / BZT, BZT, 0, stream>>>(src, dst, counts, bcursor, stage, E);
    scan1<<<nb, 256, 0, stream>>>(counts, offs, bsum, N);
    scan2<<<1, 512, 0, stream>>>(bsum, nb);
    scan3<<<nb, 256, 0, stream>>>(offs, bsum, counts, invd, N);
    fill2<<<NB * KB, 256, 0, stream>>>(stage, bcursor, offs, csr);

    // pack weights
    pack_w<<<32, 64, 0, stream>>>(W1, Wp1);
    pack_w<<<32, 64, 0, stream>>>(W2, Wp2);
    pack_w<<<32, 64, 0, stream>>>(W3, Wp3);
    pack_w<<<32, 64, 0, stream>>>(W4, Wp4);

    int gemmGrid = (N + 63) / 64;
    int aggGrid  = 8 * ((N + 127) / 128);
    int agg16Grid = (N + 127) / 128;

    gemm_mfma<1><<<gemmGrid, 256, 0, stream>>>((const void*)x, Wp1, zb, N);
    agg_sliced<<<aggGrid, 256, 0, stream>>>((const uint32*)zb, offs, counts, csr, invd, b1,
                                            (uint32*)hb, N);

    gemm_mfma<0><<<gemmGrid, 256, 0, stream>>>((const void*)hb, Wp2, zb, N);
    agg_sliced<<<aggGrid, 256, 0, stream>>>((const uint32*)zb, offs, counts, csr, invd, b2,
                                            (uint32*)hb, N);

    gemm_mfma<0><<<gemmGrid, 256, 0, stream>>>((const void*)hb, Wp3, zb, N);
    agg_sliced<<<aggGrid, 256, 0, stream>>>((const uint32*)zb, offs, counts, csr, invd, b3,
                                            (uint32*)hb, N);

    gemm_mfma<0><<<gemmGrid, 256, 0, stream>>>((const void*)hb, Wp4, zb, N);
    agg_sliced<<<aggGrid, 256, 0, stream>>>((const uint32*)zb, offs, counts, csr, invd, b4,
                                            (uint32*)hb, N);

    gemm16<<<(N * 8 + 255) / 256, 256, 0, stream>>>((const uint32*)hb, W5, z16b, N);
    agg16_lsm<<<agg16Grid, 256, 0, stream>>>(z16b, offs, counts, csr, invd, b5,
                                             (float*)d_out, N);
}